// Round 3
// baseline (205.490 us; speedup 1.0000x reference)
//
#include <hip/hip_runtime.h>
#include <cstddef>

#define BB 8
#define CC 512
#define LL 2048
#define TT 64

typedef short short8 __attribute__((ext_vector_type(8)));
typedef float floatx4 __attribute__((ext_vector_type(4)));
typedef unsigned short b16u;
typedef unsigned int u32;

static __device__ __forceinline__ unsigned f2bfu(float f) {
    unsigned u = __float_as_uint(f);
    u += 0x7fffu + ((u >> 16) & 1u);          // round-to-nearest-even
    return u >> 16;
}
static __device__ __forceinline__ float bfu2f(unsigned h) {
    return __uint_as_float(h << 16);
}

#define MFMA16(a, b, c) __builtin_amdgcn_mfma_f32_16x16x32_bf16((a), (b), (c), 0, 0, 0)

// ---------------------------------------------------------------------------
// K0: W1,W2 (64x512 fp32) -> bf16 hi/lo split, row-major.  (unchanged)
// ---------------------------------------------------------------------------
__global__ __launch_bounds__(256) void wcvt_kernel(
    const float* __restrict__ W1, const float* __restrict__ W2,
    b16u* __restrict__ W1h, b16u* __restrict__ W1l,
    b16u* __restrict__ W2h, b16u* __restrict__ W2l)
{
    int flat = blockIdx.x * 256 + threadIdx.x;        // 0..8191 float4 groups
    float4 v1 = *(const float4*)(W1 + (size_t)flat * 4);
    float4 v2 = *(const float4*)(W2 + (size_t)flat * 4);
    const float* e1 = (const float*)&v1;
    const float* e2 = (const float*)&v2;
    unsigned h1[4], l1[4], h2[4], l2[4];
#pragma unroll
    for (int k = 0; k < 4; ++k) {
        h1[k] = f2bfu(e1[k]); l1[k] = f2bfu(e1[k] - bfu2f(h1[k]));
        h2[k] = f2bfu(e2[k]); l2[k] = f2bfu(e2[k] - bfu2f(h2[k]));
    }
    uint2 a, b, c, d;
    a.x = h1[0] | (h1[1] << 16); a.y = h1[2] | (h1[3] << 16);
    b.x = l1[0] | (l1[1] << 16); b.y = l1[2] | (l1[3] << 16);
    c.x = h2[0] | (h2[1] << 16); c.y = h2[2] | (h2[3] << 16);
    d.x = l2[0] | (l2[1] << 16); d.y = l2[2] | (l2[3] << 16);
    *(uint2*)(W1h + (size_t)flat * 4) = a;
    *(uint2*)(W1l + (size_t)flat * 4) = b;
    *(uint2*)(W2h + (size_t)flat * 4) = c;
    *(uint2*)(W2l + (size_t)flat * 4) = d;
}

// ---------------------------------------------------------------------------
// K1: merged cvt+qk (unchanged): Q = W1@X, K = W2@X via split-bf16
// MFMA (hh+hl+lh) -> Qt/Kt (b, l, 64t) bf16.  grid (32 l-tiles, 8 b).
// ---------------------------------------------------------------------------
__global__ __launch_bounds__(256) void qkcvt_kernel(
    const float* __restrict__ x,
    const b16u* __restrict__ W1h, const b16u* __restrict__ W1l,
    const b16u* __restrict__ W2h, const b16u* __restrict__ W2l,
    b16u* __restrict__ Qt, b16u* __restrict__ Kt)
{
    __shared__ b16u Sxh[64 * 72];   // [l][c-chunk]
    __shared__ b16u Sxl[64 * 72];
    __shared__ b16u S1h[64 * 72];   // [t][c-chunk]
    __shared__ b16u S1l[64 * 72];
    __shared__ b16u S2h[64 * 72];
    __shared__ b16u S2l[64 * 72];
    const int b  = blockIdx.y;
    const int l0 = blockIdx.x * 64;
    const int tid = threadIdx.x;
    const int lane = tid & 63;
    const int w = tid >> 6;
    const int n16 = lane & 15;
    const int qd = lane >> 4;
    const float* xb = x + (size_t)b * CC * LL;

    const int cx = tid >> 2;
    const int sx = tid & 3;

    float4 xreg[4];
#pragma unroll
    for (int p = 0; p < 4; ++p)
        xreg[p] = *(const float4*)(xb + (size_t)cx * LL + l0 + (sx * 4 + p) * 4);

    floatx4 aq[4], ak[4];
#pragma unroll
    for (int nt = 0; nt < 4; ++nt) {
        aq[nt] = (floatx4){0.f, 0.f, 0.f, 0.f};
        ak[nt] = (floatx4){0.f, 0.f, 0.f, 0.f};
    }

    for (int c0 = 0; c0 < 512; c0 += 64) {
        __syncthreads();
#pragma unroll
        for (int p = 0; p < 4; ++p) {
            const float* e = (const float*)&xreg[p];
            int lbase = (sx * 4 + p) * 4;
#pragma unroll
            for (int k = 0; k < 4; ++k) {
                unsigned h = f2bfu(e[k]);
                unsigned lo = f2bfu(e[k] - bfu2f(h));
                Sxh[(lbase + k) * 72 + cx] = (b16u)h;
                Sxl[(lbase + k) * 72 + cx] = (b16u)lo;
            }
        }
#pragma unroll
        for (int p = 0; p < 2; ++p) {
            int flat = tid + p * 256;
            int t = flat >> 3, s8 = flat & 7;
            size_t off = (size_t)t * 512 + c0 + s8 * 8;
            *(uint4*)&S1h[t * 72 + s8 * 8] = *(const uint4*)(W1h + off);
            *(uint4*)&S1l[t * 72 + s8 * 8] = *(const uint4*)(W1l + off);
            *(uint4*)&S2h[t * 72 + s8 * 8] = *(const uint4*)(W2h + off);
            *(uint4*)&S2l[t * 72 + s8 * 8] = *(const uint4*)(W2l + off);
        }
        __syncthreads();
        if (c0 < 448) {
#pragma unroll
            for (int p = 0; p < 4; ++p)
                xreg[p] = *(const float4*)(xb + (size_t)(c0 + 64 + cx) * LL +
                                           l0 + (sx * 4 + p) * 4);
        }
#pragma unroll
        for (int kc = 0; kc < 2; ++kc) {
            const int ao = (w * 16 + n16) * 72 + kc * 32 + qd * 8;
            short8 a1h = *(const short8*)&S1h[ao];
            short8 a1l = *(const short8*)&S1l[ao];
            short8 a2h = *(const short8*)&S2h[ao];
            short8 a2l = *(const short8*)&S2l[ao];
#pragma unroll
            for (int nt = 0; nt < 4; ++nt) {
                const int bo = (nt * 16 + n16) * 72 + kc * 32 + qd * 8;
                short8 bh = *(const short8*)&Sxh[bo];
                short8 bl = *(const short8*)&Sxl[bo];
                aq[nt] = MFMA16(a1h, bh, aq[nt]);
                aq[nt] = MFMA16(a1h, bl, aq[nt]);
                aq[nt] = MFMA16(a1l, bh, aq[nt]);
                ak[nt] = MFMA16(a2h, bh, ak[nt]);
                ak[nt] = MFMA16(a2h, bl, ak[nt]);
                ak[nt] = MFMA16(a2l, bh, ak[nt]);
            }
        }
    }
#pragma unroll
    for (int nt = 0; nt < 4; ++nt) {
        int l = l0 + nt * 16 + n16;
        uint2 pq, pk;
        pq.x = f2bfu(aq[nt][0]) | (f2bfu(aq[nt][1]) << 16);
        pq.y = f2bfu(aq[nt][2]) | (f2bfu(aq[nt][3]) << 16);
        pk.x = f2bfu(ak[nt][0]) | (f2bfu(ak[nt][1]) << 16);
        pk.y = f2bfu(ak[nt][2]) | (f2bfu(ak[nt][3]) << 16);
        *(uint2*)(Qt + ((size_t)(b * 2048) + l) * 64 + w * 16 + qd * 4) = pq;
        *(uint2*)(Kt + ((size_t)(b * 2048) + l) * 64 + w * 16 + qd * 4) = pk;
    }
}

// ---------------------------------------------------------------------------
// K2: x -> XT bf16, TILE-MAJOR (b, t=32, c=512, 64i).  (unchanged from R2)
// ---------------------------------------------------------------------------
__global__ __launch_bounds__(256) void xcvt_kernel(
    const float* __restrict__ x, b16u* __restrict__ XT)
{
    int flat = blockIdx.x * 256 + threadIdx.x;   // 0..2097151 float4 groups
    int i4 = flat & 15;
    int t  = (flat >> 4) & 31;
    int c  = (flat >> 9) & 511;
    int b  = flat >> 18;
    float4 v = *(const float4*)(x + ((size_t)(b * 512 + c)) * 2048 + t * 64 + i4 * 4);
    uint2 wv;
    wv.x = f2bfu(v.x) | (f2bfu(v.y) << 16);
    wv.y = f2bfu(v.z) | (f2bfu(v.w) << 16);
    *(uint2*)(XT + (((size_t)(b * 32) + t) * 512 + c) * 64 + i4 * 4) = wv;
}

// ---------------------------------------------------------------------------
// K3: fused attention, PRODUCER-CONSUMER wave specialization.
// grid 256 (bid&7 = batch -> XCD L2 holds the 2 MB XT slab; bid>>3 = j-tile
// of 64), block 768 = 12 waves (3/SIMD: each SIMD gets 1 S-wave + 2 PV-waves).
//   S-waves (w 0..3): own i-strip w*16; per tile: K double-buffered in regs,
//     8 MFMA -> exp(S-20) -> pack bf16 -> 4 ds_write to swizzled P tile.
//     All transcendental/pack VALU is confined to these 4 waves.
//   PV-waves (w 4..11): own c-strip (w-4)*64 (full 512 c -> S computed ONCE);
//     per tile: 8 contiguous V loads (tile-major XT), 8 swizzled ds_read_b128,
//     32 MFMA into 4x4 acc.  MFMA-dense ~80-instruction body.
// One barrier per tile; P double-buffered (8 KB each); barriers convergent.
// ---------------------------------------------------------------------------
__global__ __launch_bounds__(768, 3) void fused_kernel(
    const float* __restrict__ x, const b16u* __restrict__ XT,
    const b16u* __restrict__ Qt, const b16u* __restrict__ Kt,
    const float* __restrict__ gamma, float* __restrict__ out)
{
    // [0,16384): Ps[2][64j][64i] shorts.  Epilogue reuses [0,139264) as 8
    // per-PV-wave staging buffers (64x68 fp32).  Zw/Zf live above both.
    __shared__ __align__(16) char smem[140544];
    b16u*  Ps = (b16u*)smem;
    float* Zw = (float*)(smem + 139264);        // [4][64]
    float* Zf = (float*)(smem + 140288);        // [64]

    const int bid = blockIdx.x;
    const int b   = bid & 7;
    const int j0  = (bid >> 3) * 64;
    const int tid = threadIdx.x;
    const int lane = tid & 63;
    const int w    = tid >> 6;                  // 0..11 (wave-uniform)
    const int n16  = lane & 15;
    const int qd   = lane >> 4;

    const b16u* Qb = Qt + ((size_t)(b * LL) + j0 + n16) * 64 + qd * 8;
    const b16u* Kb = Kt + ((size_t)(b * LL) + (w & 3) * 16 + n16) * 64 + qd * 8;
    const b16u* Vb = XT + (size_t)b * (32 * 32768) +
                     ((size_t)((w - 4) * 64 + n16)) * 64 + qd * 8;

    short8 qf[4][2];                 // S-waves: loop-invariant Q B-frags
    short8 kA[2], kB[2];             // S-waves: K double-buffer
    float  zacc[4] = {0.f, 0.f, 0.f, 0.f};
    floatx4 acc[4][4];               // PV-waves: 64c x 64j accumulator
    short8 av[4][2];                 // PV-waves: V A-frags for current tile

#define KLOAD(KR, T)                                                       \
    {                                                                      \
        const b16u* kp = Kb + (size_t)(T) * 4096;                          \
        KR[0] = *(const short8*)(kp);                                      \
        KR[1] = *(const short8*)(kp + 32);                                 \
    }

#define VLOAD(T)                                                           \
    {                                                                      \
        const b16u* vp = Vb + (size_t)(T) * 32768;                         \
        _Pragma("unroll")                                                  \
        for (int mt = 0; mt < 4; ++mt) {                                   \
            av[mt][0] = *(const short8*)(vp + mt * 1024);                  \
            av[mt][1] = *(const short8*)(vp + mt * 1024 + 32);             \
        }                                                                  \
    }

    // S tile: D[m = i-local (strip w&3), n = j]; lane holds 4 consecutive i
    // at fixed j -> 8B write into 16B-chunk XOR-swizzled row (key j&7=n16&7)
#define SSTEP(PSOFF, KR)                                                   \
    {                                                                      \
        _Pragma("unroll")                                                  \
        for (int nt = 0; nt < 4; ++nt) {                                   \
            floatx4 sacc = (floatx4){0.f, 0.f, 0.f, 0.f};                  \
            sacc = MFMA16(KR[0], qf[nt][0], sacc);                         \
            sacc = MFMA16(KR[1], qf[nt][1], sacc);                         \
            float p0 = __expf(sacc[0] - 20.0f);                            \
            float p1 = __expf(sacc[1] - 20.0f);                            \
            float p2 = __expf(sacc[2] - 20.0f);                            \
            float p3 = __expf(sacc[3] - 20.0f);                            \
            zacc[nt] += (p0 + p1) + (p2 + p3);                             \
            uint2 pk;                                                      \
            pk.x = f2bfu(p0) | (f2bfu(p1) << 16);                          \
            pk.y = f2bfu(p2) | (f2bfu(p3) << 16);                          \
            int jl = nt * 16 + n16;                                        \
            int phys = ((w & 3) * 2 + (qd >> 1)) ^ (n16 & 7);              \
            *(uint2*)&Ps[(PSOFF) + jl * 64 + phys * 8 + (qd & 1) * 4] = pk;\
        }                                                                  \
    }

#define PVSTEP(PSOFF)                                                      \
    {                                                                      \
        __builtin_amdgcn_s_setprio(1);                                     \
        _Pragma("unroll")                                                  \
        for (int kc = 0; kc < 2; ++kc) {                                   \
            short8 bfr[4];                                                 \
            _Pragma("unroll")                                              \
            for (int nt = 0; nt < 4; ++nt) {                               \
                int phys = (kc * 4 + qd) ^ (n16 & 7);                      \
                bfr[nt] = *(const short8*)&Ps[(PSOFF) +                    \
                    (nt * 16 + n16) * 64 + phys * 8];                      \
            }                                                              \
            _Pragma("unroll")                                              \
            for (int mt = 0; mt < 4; ++mt)                                 \
                _Pragma("unroll")                                          \
                for (int nt = 0; nt < 4; ++nt)                             \
                    acc[mt][nt] = MFMA16(av[mt][kc], bfr[nt], acc[mt][nt]);\
        }                                                                  \
        __builtin_amdgcn_s_setprio(0);                                     \
    }

    // -------- prologue --------
    if (w < 4) {
#pragma unroll
        for (int nt = 0; nt < 4; ++nt) {
            qf[nt][0] = *(const short8*)(Qb + nt * 1024);
            qf[nt][1] = *(const short8*)(Qb + nt * 1024 + 32);
        }
        KLOAD(kA, 0)
        SSTEP(0, kA)                  // tile 0 -> Ps0
        KLOAD(kA, 1)
    } else {
#pragma unroll
        for (int mt = 0; mt < 4; ++mt)
#pragma unroll
            for (int nt = 0; nt < 4; ++nt)
                acc[mt][nt] = (floatx4){0.f, 0.f, 0.f, 0.f};
        VLOAD(0)
    }
    __syncthreads();

    // -------- main loop: 32 i-tiles, 1 barrier/tile --------
    for (int tt = 0; tt < 32; tt += 2) {
        if (w < 4) {
            SSTEP(4096, kA)           // tile tt+1 -> Ps1 (kA = K(tt+1))
            if (tt + 2 < 32) KLOAD(kB, tt + 2)
        } else {
            PVSTEP(0)                 // tile tt from Ps0 (av = V(tt))
            VLOAD(tt + 1)
        }
        __syncthreads();
        if (w < 4) {
            if (tt + 2 < 32) {
                SSTEP(0, kB)          // tile tt+2 -> Ps0 (kB = K(tt+2))
                if (tt + 3 < 32) KLOAD(kA, tt + 3)
            }
        } else {
            PVSTEP(4096)              // tile tt+1 from Ps1 (av = V(tt+1))
            if (tt + 2 < 32) VLOAD(tt + 2)
        }
        __syncthreads();
    }
#undef KLOAD
#undef VLOAD
#undef SSTEP
#undef PVSTEP

    // -------- Z: shfl-reduce over qd, then over the 4 S-waves --------
    if (w < 4) {
#pragma unroll
        for (int nt = 0; nt < 4; ++nt) {
            float z = zacc[nt];
            z += __shfl_xor(z, 16);
            z += __shfl_xor(z, 32);
            if (qd == 0) Zw[w * 64 + nt * 16 + n16] = z;
        }
    }
    __syncthreads();
    if (tid < 64)
        Zf[tid] = Zw[tid] + Zw[64 + tid] + Zw[128 + tid] + Zw[192 + tid];
    __syncthreads();

    // -------- epilogue (PV waves): scale g/Z, LDS transpose, store --------
    const float g = gamma[0];
    if (w >= 4) {
        float* st = (float*)(smem + (w - 4) * 17408);   // 64 x 68 floats
#pragma unroll
        for (int nt = 0; nt < 4; ++nt) {
            float zi = g / Zf[nt * 16 + n16];
#pragma unroll
            for (int mt = 0; mt < 4; ++mt)
#pragma unroll
                for (int r = 0; r < 4; ++r)
                    st[(mt * 16 + qd * 4 + r) * 68 + nt * 16 + n16] =
                        acc[mt][nt][r] * zi;
        }
    }
    __syncthreads();
    if (w >= 4) {
        const float* st = (const float*)(smem + (w - 4) * 17408);
#pragma unroll
        for (int p = 0; p < 16; ++p) {
            int rl = qd * 16 + p;                       // c-local row
            int cg = (w - 4) * 64 + rl;
            size_t go = ((size_t)(b * CC) + cg) * 2048 + j0 + n16 * 4;
            float4 v = *(const float4*)&st[rl * 68 + n16 * 4];
            float4 xv = *(const float4*)(x + go);
            v.x += xv.x; v.y += xv.y; v.z += xv.z; v.w += xv.w;
            *(float4*)(out + go) = v;
        }
    }
}

// ---------------------------------------------------------------------------
extern "C" void kernel_launch(void* const* d_in, const int* in_sizes, int n_in,
                              void* d_out, int out_size, void* d_ws, size_t ws_size,
                              hipStream_t stream)
{
    (void)in_sizes; (void)n_in; (void)out_size; (void)ws_size;
    const float* x     = (const float*)d_in[0];
    const float* W1    = (const float*)d_in[1];
    const float* W2    = (const float*)d_in[2];
    const float* gamma = (const float*)d_in[3];
    float* out = (float*)d_out;

    b16u* Qt  = (b16u*)d_ws;                        // 2 MB
    b16u* Kt  = Qt  + (size_t)BB * LL * TT;         // 2 MB
    b16u* W1h = Kt  + (size_t)BB * LL * TT;         // 64 KB x4
    b16u* W1l = W1h + (size_t)TT * CC;
    b16u* W2h = W1l + (size_t)TT * CC;
    b16u* W2l = W2h + (size_t)TT * CC;
    b16u* XT  = W2l + (size_t)TT * CC;              // 16.8 MB, (b,t,c,64) bf16

    wcvt_kernel <<<dim3(32),      256, 0, stream>>>(W1, W2, W1h, W1l, W2h, W2l);
    xcvt_kernel <<<dim3(8192),    256, 0, stream>>>(x, XT);
    qkcvt_kernel<<<dim3(32, BB),  256, 0, stream>>>(x, W1h, W1l, W2h, W2l, Qt, Kt);
    fused_kernel<<<dim3(256),     768, 0, stream>>>(x, XT, Qt, Kt, gamma, out);
}

// Round 4
// 197.501 us; speedup vs baseline: 1.0405x; 1.0405x over previous
//
#include <hip/hip_runtime.h>
#include <cstddef>

#define BB 8
#define CC 512
#define LL 2048
#define TT 64

typedef short short8 __attribute__((ext_vector_type(8)));
typedef float floatx4 __attribute__((ext_vector_type(4)));
typedef unsigned short b16u;
typedef unsigned int u32;

#define LOG2E 1.44269504088896f
#define NEG20LOG2E -28.8539008177793f

static __device__ __forceinline__ unsigned f2bfu(float f) {
    unsigned u = __float_as_uint(f);
    u += 0x7fffu + ((u >> 16) & 1u);          // round-to-nearest-even
    return u >> 16;
}
static __device__ __forceinline__ float bfu2f(unsigned h) {
    return __uint_as_float(h << 16);
}

#define MFMA16(a, b, c) __builtin_amdgcn_mfma_f32_16x16x32_bf16((a), (b), (c), 0, 0, 0)

// ---------------------------------------------------------------------------
// K0: W1,W2 (64x512 fp32) -> bf16 hi/lo split, row-major.  (unchanged)
// ---------------------------------------------------------------------------
__global__ __launch_bounds__(256) void wcvt_kernel(
    const float* __restrict__ W1, const float* __restrict__ W2,
    b16u* __restrict__ W1h, b16u* __restrict__ W1l,
    b16u* __restrict__ W2h, b16u* __restrict__ W2l)
{
    int flat = blockIdx.x * 256 + threadIdx.x;        // 0..8191 float4 groups
    float4 v1 = *(const float4*)(W1 + (size_t)flat * 4);
    float4 v2 = *(const float4*)(W2 + (size_t)flat * 4);
    const float* e1 = (const float*)&v1;
    const float* e2 = (const float*)&v2;
    unsigned h1[4], l1[4], h2[4], l2[4];
#pragma unroll
    for (int k = 0; k < 4; ++k) {
        h1[k] = f2bfu(e1[k]); l1[k] = f2bfu(e1[k] - bfu2f(h1[k]));
        h2[k] = f2bfu(e2[k]); l2[k] = f2bfu(e2[k] - bfu2f(h2[k]));
    }
    uint2 a, b, c, d;
    a.x = h1[0] | (h1[1] << 16); a.y = h1[2] | (h1[3] << 16);
    b.x = l1[0] | (l1[1] << 16); b.y = l1[2] | (l1[3] << 16);
    c.x = h2[0] | (h2[1] << 16); c.y = h2[2] | (h2[3] << 16);
    d.x = l2[0] | (l2[1] << 16); d.y = l2[2] | (l2[3] << 16);
    *(uint2*)(W1h + (size_t)flat * 4) = a;
    *(uint2*)(W1l + (size_t)flat * 4) = b;
    *(uint2*)(W2h + (size_t)flat * 4) = c;
    *(uint2*)(W2l + (size_t)flat * 4) = d;
}

// ---------------------------------------------------------------------------
// K1: merged prep: reads x ONCE per tile; emits (a) XT bf16 tile-major
// (b,t,c,64i) for the fused V path, (b) Qt scaled by log2(e) and Kt via
// split-bf16 MFMA (hh+hl+lh).  grid (32 l-tiles, 8 b), 256 threads.
// ---------------------------------------------------------------------------
__global__ __launch_bounds__(256) void prep_kernel(
    const float* __restrict__ x,
    const b16u* __restrict__ W1h, const b16u* __restrict__ W1l,
    const b16u* __restrict__ W2h, const b16u* __restrict__ W2l,
    b16u* __restrict__ Qt, b16u* __restrict__ Kt, b16u* __restrict__ XT)
{
    __shared__ b16u Sxh[64 * 72];   // [l][c-chunk]
    __shared__ b16u Sxl[64 * 72];
    __shared__ b16u S1h[64 * 72];   // [t][c-chunk]
    __shared__ b16u S1l[64 * 72];
    __shared__ b16u S2h[64 * 72];
    __shared__ b16u S2l[64 * 72];
    const int b  = blockIdx.y;
    const int lt = blockIdx.x;
    const int l0 = lt * 64;
    const int tid = threadIdx.x;
    const int lane = tid & 63;
    const int w = tid >> 6;
    const int n16 = lane & 15;
    const int qd = lane >> 4;
    const float* xb = x + (size_t)b * CC * LL;

    const int cx = tid >> 2;
    const int sx = tid & 3;

    float4 xreg[4];
#pragma unroll
    for (int p = 0; p < 4; ++p)
        xreg[p] = *(const float4*)(xb + (size_t)cx * LL + l0 + (sx * 4 + p) * 4);

    floatx4 aq[4], ak[4];
#pragma unroll
    for (int nt = 0; nt < 4; ++nt) {
        aq[nt] = (floatx4){0.f, 0.f, 0.f, 0.f};
        ak[nt] = (floatx4){0.f, 0.f, 0.f, 0.f};
    }

    for (int c0 = 0; c0 < 512; c0 += 64) {
        __syncthreads();
#pragma unroll
        for (int p = 0; p < 4; ++p) {
            const float* e = (const float*)&xreg[p];
            int lbase = (sx * 4 + p) * 4;
            unsigned hh[4];
#pragma unroll
            for (int k = 0; k < 4; ++k) {
                unsigned h = f2bfu(e[k]);
                unsigned lo = f2bfu(e[k] - bfu2f(h));
                hh[k] = h;
                Sxh[(lbase + k) * 72 + cx] = (b16u)h;
                Sxl[(lbase + k) * 72 + cx] = (b16u)lo;
            }
            // XT emit: tile-major (b, t=lt, c, 64i); 16 consecutive i per
            // thread at fixed c -> 4x uint2 stores.
            uint2 wv;
            wv.x = hh[0] | (hh[1] << 16);
            wv.y = hh[2] | (hh[3] << 16);
            *(uint2*)(XT + (((size_t)(b * 32) + lt) * 512 + c0 + cx) * 64 + lbase) = wv;
        }
#pragma unroll
        for (int p = 0; p < 2; ++p) {
            int flat = tid + p * 256;
            int t = flat >> 3, s8 = flat & 7;
            size_t off = (size_t)t * 512 + c0 + s8 * 8;
            *(uint4*)&S1h[t * 72 + s8 * 8] = *(const uint4*)(W1h + off);
            *(uint4*)&S1l[t * 72 + s8 * 8] = *(const uint4*)(W1l + off);
            *(uint4*)&S2h[t * 72 + s8 * 8] = *(const uint4*)(W2h + off);
            *(uint4*)&S2l[t * 72 + s8 * 8] = *(const uint4*)(W2l + off);
        }
        __syncthreads();
        if (c0 < 448) {
#pragma unroll
            for (int p = 0; p < 4; ++p)
                xreg[p] = *(const float4*)(xb + (size_t)(c0 + 64 + cx) * LL +
                                           l0 + (sx * 4 + p) * 4);
        }
#pragma unroll
        for (int kc = 0; kc < 2; ++kc) {
            const int ao = (w * 16 + n16) * 72 + kc * 32 + qd * 8;
            short8 a1h = *(const short8*)&S1h[ao];
            short8 a1l = *(const short8*)&S1l[ao];
            short8 a2h = *(const short8*)&S2h[ao];
            short8 a2l = *(const short8*)&S2l[ao];
#pragma unroll
            for (int nt = 0; nt < 4; ++nt) {
                const int bo = (nt * 16 + n16) * 72 + kc * 32 + qd * 8;
                short8 bh = *(const short8*)&Sxh[bo];
                short8 bl = *(const short8*)&Sxl[bo];
                aq[nt] = MFMA16(a1h, bh, aq[nt]);
                aq[nt] = MFMA16(a1h, bl, aq[nt]);
                aq[nt] = MFMA16(a1l, bh, aq[nt]);
                ak[nt] = MFMA16(a2h, bh, ak[nt]);
                ak[nt] = MFMA16(a2h, bl, ak[nt]);
                ak[nt] = MFMA16(a2l, bh, ak[nt]);
            }
        }
    }
#pragma unroll
    for (int nt = 0; nt < 4; ++nt) {
        int l = l0 + nt * 16 + n16;
        uint2 pq, pk;
        // Q scaled by log2(e): fused kernel computes P = exp2(S*log2e - 20*log2e)
        pq.x = f2bfu(aq[nt][0] * LOG2E) | (f2bfu(aq[nt][1] * LOG2E) << 16);
        pq.y = f2bfu(aq[nt][2] * LOG2E) | (f2bfu(aq[nt][3] * LOG2E) << 16);
        pk.x = f2bfu(ak[nt][0]) | (f2bfu(ak[nt][1]) << 16);
        pk.y = f2bfu(ak[nt][2]) | (f2bfu(ak[nt][3]) << 16);
        *(uint2*)(Qt + ((size_t)(b * 2048) + l) * 64 + w * 16 + qd * 4) = pq;
        *(uint2*)(Kt + ((size_t)(b * 2048) + l) * 64 + w * 16 + qd * 4) = pk;
    }
}

// ---------------------------------------------------------------------------
// K2: fused flash attention v3.  grid 512 = 8b x 32jt x 2ch (bid&7 = batch ->
// XCD L2 locality), 512 threads = 8 waves, 17.7 KB LDS -> 2 BLOCKS/CU so the
// two barrier groups interleave (the R1-R3 killer was 1 group/CU).
// Per block: j-tile 64, c-half 256, loop 32 i-tiles:
//   S-role: wave (si=w&3 i-strip16, sj=w>>2 j-half32): 4 MFMA with acc init
//     -20*log2e -> P = v_exp_f32(sacc) directly -> v_cvt_pk_bf16_f32 pack ->
//     2x 8B ds_write into XOR-swizzled Ps (double-buffered, 8 KB each).
//   PV-role: wave c-strip w*32: V from regs (tile-major XT, contiguous),
//     8 swizzled ds_read_b128, 16 MFMA into acc[2][4].
// One barrier per tile.  Epilogue: Z shfl+LDS reduce, direct stores.
// ---------------------------------------------------------------------------
__global__ __launch_bounds__(512, 4) void fused_kernel(
    const float* __restrict__ x, const b16u* __restrict__ XT,
    const b16u* __restrict__ Qt, const b16u* __restrict__ Kt,
    const float* __restrict__ gamma, float* __restrict__ out)
{
    __shared__ __align__(16) char smem[17664];
    b16u*  Ps = (b16u*)smem;                    // [2][64j][64i] shorts
    float* Zw = (float*)(smem + 16384);         // [8][32]
    float* Zf = (float*)(smem + 17408);         // [64]

    const int bid = blockIdx.x;
    const int b   = bid & 7;
    const int jt  = (bid >> 3) & 31;
    const int ch  = bid >> 8;
    const int j0  = jt * 64;
    const int c0  = ch * 256;
    const int tid = threadIdx.x;
    const int lane = tid & 63;
    const int w    = tid >> 6;
    const int n16  = lane & 15;
    const int qd   = lane >> 4;
    const int si   = w & 3;        // S: i-strip (16 rows)
    const int sj   = w >> 2;       // S: j-half (32 cols)

    const b16u* Qb = Qt + ((size_t)(b * LL) + j0 + sj * 32 + n16) * 64 + qd * 8;
    const b16u* Kb = Kt + ((size_t)(b * LL) + si * 16 + n16) * 64 + qd * 8;
    const b16u* Vb = XT + (size_t)b * (32 * 32768) +
                     (size_t)(c0 + w * 32 + n16) * 64 + qd * 8;

    short8 qf[2][2];
#pragma unroll
    for (int nt = 0; nt < 2; ++nt)
#pragma unroll
        for (int kc = 0; kc < 2; ++kc)
            qf[nt][kc] = *(const short8*)(Qb + nt * 1024 + kc * 32);

    floatx4 acc[2][4];
#pragma unroll
    for (int mt = 0; mt < 2; ++mt)
#pragma unroll
        for (int nt = 0; nt < 4; ++nt) acc[mt][nt] = (floatx4){0.f, 0.f, 0.f, 0.f};
    float zacc[2] = {0.f, 0.f};

    short8 kA[2], kB[2], av[2][2];

#define KLOAD(KR, T)                                                       \
    {                                                                      \
        const b16u* kp = Kb + (size_t)(T) * 4096;                          \
        KR[0] = *(const short8*)(kp);                                      \
        KR[1] = *(const short8*)(kp + 32);                                 \
    }

#define VLOAD(T)                                                           \
    {                                                                      \
        const b16u* vp = Vb + (size_t)(T) * 32768;                         \
        _Pragma("unroll")                                                  \
        for (int mt = 0; mt < 2; ++mt) {                                   \
            av[mt][0] = *(const short8*)(vp + mt * 1024);                  \
            av[mt][1] = *(const short8*)(vp + mt * 1024 + 32);             \
        }                                                                  \
    }

    // S: D[m = i-local (si strip), n = j (sj half)]; lane holds 4 consecutive
    // i at fixed j.  acc init -20*log2e; Qt pre-scaled by log2e -> P=exp2(sacc)
#define SSTEP(PSOFF, KR)                                                   \
    {                                                                      \
        _Pragma("unroll")                                                  \
        for (int nt = 0; nt < 2; ++nt) {                                   \
            floatx4 sacc = (floatx4){NEG20LOG2E, NEG20LOG2E,               \
                                     NEG20LOG2E, NEG20LOG2E};              \
            sacc = MFMA16(KR[0], qf[nt][0], sacc);                         \
            sacc = MFMA16(KR[1], qf[nt][1], sacc);                         \
            float p0 = __builtin_amdgcn_exp2f(sacc[0]);                    \
            float p1 = __builtin_amdgcn_exp2f(sacc[1]);                    \
            float p2 = __builtin_amdgcn_exp2f(sacc[2]);                    \
            float p3 = __builtin_amdgcn_exp2f(sacc[3]);                    \
            zacc[nt] += (p0 + p1) + (p2 + p3);                             \
            uint2 pk;                                                      \
            asm("v_cvt_pk_bf16_f32 %0, %1, %2" : "=v"(pk.x)                \
                : "v"(p0), "v"(p1));                                       \
            asm("v_cvt_pk_bf16_f32 %0, %1, %2" : "=v"(pk.y)                \
                : "v"(p2), "v"(p3));                                       \
            int jl = sj * 32 + nt * 16 + n16;                              \
            int phys = (si * 2 + (qd >> 1)) ^ (n16 & 7);                   \
            *(uint2*)&Ps[(PSOFF) + jl * 64 + phys * 8 + (qd & 1) * 4] = pk;\
        }                                                                  \
    }

#define PVSTEP(PSOFF)                                                      \
    {                                                                      \
        _Pragma("unroll")                                                  \
        for (int kc = 0; kc < 2; ++kc) {                                   \
            short8 bfr[4];                                                 \
            _Pragma("unroll")                                              \
            for (int nt = 0; nt < 4; ++nt) {                               \
                int phys = (kc * 4 + qd) ^ (n16 & 7);                      \
                bfr[nt] = *(const short8*)&Ps[(PSOFF) +                    \
                    (nt * 16 + n16) * 64 + phys * 8];                      \
            }                                                              \
            _Pragma("unroll")                                              \
            for (int mt = 0; mt < 2; ++mt)                                 \
                _Pragma("unroll")                                          \
                for (int nt = 0; nt < 4; ++nt)                             \
                    acc[mt][nt] = MFMA16(av[mt][kc], bfr[nt], acc[mt][nt]);\
        }                                                                  \
    }

    // -------- prologue: S(0) -> Ps0; K(1) prefetched --------
    KLOAD(kA, 0)
    SSTEP(0, kA)
    KLOAD(kB, 1)
    __syncthreads();

    // -------- main loop: 1 barrier/tile; V loaded at phase start --------
    for (int tt = 0; tt < 32; tt += 2) {
        VLOAD(tt)
        SSTEP(4096, kB)                        // S(tt+1) -> Ps1
        if (tt + 2 < 32) KLOAD(kA, tt + 2)
        PVSTEP(0)                              // PV(tt) from Ps0
        __syncthreads();
        VLOAD(tt + 1)
        if (tt + 2 < 32) SSTEP(0, kA)          // S(tt+2) -> Ps0
        if (tt + 3 < 32) KLOAD(kB, tt + 3)
        PVSTEP(4096)                           // PV(tt+1) from Ps1
        __syncthreads();
    }
#undef KLOAD
#undef VLOAD
#undef SSTEP
#undef PVSTEP

    // -------- Z: shfl over qd, then over the 4 si-strips --------
#pragma unroll
    for (int nt = 0; nt < 2; ++nt) {
        float z = zacc[nt];
        z += __shfl_xor(z, 16);
        z += __shfl_xor(z, 32);
        if (qd == 0) Zw[w * 32 + nt * 16 + n16] = z;
    }
    __syncthreads();
    if (tid < 64) {
        int sjj = tid >> 5, v = tid & 31;
        Zf[tid] = Zw[(sjj * 4 + 0) * 32 + v] + Zw[(sjj * 4 + 1) * 32 + v] +
                  Zw[(sjj * 4 + 2) * 32 + v] + Zw[(sjj * 4 + 3) * 32 + v];
    }
    __syncthreads();

    // -------- epilogue: direct stores (no LDS staging) --------
    const float g = gamma[0];
#pragma unroll
    for (int nt = 0; nt < 4; ++nt) {
        float zi = g / Zf[nt * 16 + n16];
#pragma unroll
        for (int mt = 0; mt < 2; ++mt)
#pragma unroll
            for (int r = 0; r < 4; ++r) {
                int cg = c0 + w * 32 + mt * 16 + qd * 4 + r;
                size_t go = ((size_t)(b * CC) + cg) * 2048 + j0 + nt * 16 + n16;
                out[go] = x[go] + acc[mt][nt][r] * zi;
            }
    }
}

// ---------------------------------------------------------------------------
extern "C" void kernel_launch(void* const* d_in, const int* in_sizes, int n_in,
                              void* d_out, int out_size, void* d_ws, size_t ws_size,
                              hipStream_t stream)
{
    (void)in_sizes; (void)n_in; (void)out_size; (void)ws_size;
    const float* x     = (const float*)d_in[0];
    const float* W1    = (const float*)d_in[1];
    const float* W2    = (const float*)d_in[2];
    const float* gamma = (const float*)d_in[3];
    float* out = (float*)d_out;

    b16u* Qt  = (b16u*)d_ws;                        // 2 MB (log2e-scaled)
    b16u* Kt  = Qt  + (size_t)BB * LL * TT;         // 2 MB
    b16u* W1h = Kt  + (size_t)BB * LL * TT;         // 64 KB x4
    b16u* W1l = W1h + (size_t)TT * CC;
    b16u* W2h = W1l + (size_t)TT * CC;
    b16u* W2l = W2h + (size_t)TT * CC;
    b16u* XT  = W2l + (size_t)TT * CC;              // 16.8 MB, (b,t,c,64) bf16

    wcvt_kernel<<<dim3(32),     256, 0, stream>>>(W1, W2, W1h, W1l, W2h, W2l);
    prep_kernel<<<dim3(32, BB), 256, 0, stream>>>(x, W1h, W1l, W2h, W2l,
                                                  Qt, Kt, XT);
    fused_kernel<<<dim3(512),   512, 0, stream>>>(x, XT, Qt, Kt, gamma, out);
}